// Round 7
// baseline (124.816 us; speedup 1.0000x reference)
//
#include <hip/hip_runtime.h>
#include <math.h>

#define B_ 16
#define S_ 4
#define T_ 1000
#define D_ 256
#define N_ 8192
#define V_ 50000

constexpr int NC1 = 20;              // chunks over T for k1
constexpr int TC1 = (T_ + NC1 - 1) / NC1;  // 50 frames per chunk
constexpr int NCSE = 32;             // SE chunks over N
constexpr int CPSE = N_ / NCSE;      // 256 candidates per chunk

// GEMM tile (kG)
constexpr int GR   = 64;             // table rows per block
constexpr int GDCH = 32;             // d-chunk
constexpr int GPAD = GDCH + 4;       // padded LDS stride (36 floats)
constexpr int GNB  = (V_ + GR - 1) / GR;   // 782 blocks

// ws layout (float units) — small arrays FIRST so the fallback path fits
constexpr size_t OFF_W   = 0;                                // [64][NC1][D]
constexpr size_t OFF_CNT = OFF_W   + (size_t)64*NC1*D_;      // [64][NC1]
constexpr size_t OFF_E   = OFF_CNT + (size_t)64*NC1;         // [64][D]
constexpr size_t OFF_IDX = OFF_E   + (size_t)64*D_;          // [64] int
constexpr size_t OFF_ACT = OFF_IDX + 64;                     // [64]
constexpr size_t OFF_DT  = OFF_ACT + 64;                     // [64]
constexpr size_t OFF_SE  = OFF_DT  + 64;                     // [B][NCSE][S]
constexpr size_t OFF_DOT = OFF_SE  + (size_t)B_*NCSE*S_;     // [V][64]
constexpr size_t WS_SMALL_FLOATS = OFF_DOT;
constexpr size_t WS_FULL_FLOATS  = OFF_DOT + (size_t)V_*64;

// ---------------------------------------------------------------- kernel 1
__global__ __launch_bounds__(256) void k1_frames(
    const float* __restrict__ spks, const float* __restrict__ ts,
    const int* __restrict__ sigmas, const int* __restrict__ ilens,
    float* __restrict__ Wp, float* __restrict__ Cp)
{
    const int blk   = blockIdx.x;
    const int bs    = blk / NC1;
    const int chunk = blk % NC1;
    const int b = bs / S_, s = bs % S_;
    const int sig  = sigmas[b * S_ + s];
    const int ilen = ilens[b];
    const int t0 = chunk * TC1;
    int t1 = t0 + TC1; if (t1 > T_) t1 = T_; if (t1 > ilen) t1 = ilen;

    const int wid  = threadIdx.x >> 6;
    const int lane = threadIdx.x & 63;

    float4 acc = make_float4(0.f, 0.f, 0.f, 0.f);
    float  cnt = 0.f;
    const float* base = spks + (size_t)bs * T_ * D_;

    for (int t = t0 + wid; t < t1; t += 4) {
        float4 v = *(const float4*)(base + (size_t)t * D_ + lane * 4);
        float n2 = v.x * v.x + v.y * v.y + v.z * v.z + v.w * v.w;
        #pragma unroll
        for (int o = 32; o >= 1; o >>= 1) n2 += __shfl_xor(n2, o, 64);
        const float w = ts[(b * T_ + t) * S_ + sig];
        const float scale = w / sqrtf(n2);
        acc.x += v.x * scale; acc.y += v.y * scale;
        acc.z += v.z * scale; acc.w += v.w * scale;
        if (lane == 0) cnt += rintf(w);
    }

    __shared__ float sacc[4][D_];
    __shared__ float scnt[4];
    sacc[wid][lane * 4 + 0] = acc.x;
    sacc[wid][lane * 4 + 1] = acc.y;
    sacc[wid][lane * 4 + 2] = acc.z;
    sacc[wid][lane * 4 + 3] = acc.w;
    if (lane == 0) scnt[wid] = cnt;
    __syncthreads();

    const int d = threadIdx.x;
    const float sum = sacc[0][d] + sacc[1][d] + sacc[2][d] + sacc[3][d];
    Wp[((size_t)bs * NC1 + chunk) * D_ + d] = sum;
    if (threadIdx.x == 0)
        Cp[(size_t)bs * NC1 + chunk] = scnt[0] + scnt[1] + scnt[2] + scnt[3];
}

// ---------------------------------------------------------------- kernel 2
__global__ __launch_bounds__(256) void k2_evec(
    const float* __restrict__ Wp, const float* __restrict__ Cp,
    const int* __restrict__ ss, const int* __restrict__ sigmas,
    float* __restrict__ E, int* __restrict__ IDX, float* __restrict__ ACT)
{
    const int bs = blockIdx.x;
    const int d  = threadIdx.x;
    float sum = 0.f;
    for (int c = 0; c < NC1; ++c) sum += Wp[((size_t)bs * NC1 + c) * D_ + d];

    float n2 = sum * sum;
    #pragma unroll
    for (int o = 32; o >= 1; o >>= 1) n2 += __shfl_xor(n2, o, 64);
    __shared__ float wsum[4];
    if ((threadIdx.x & 63) == 0) wsum[threadIdx.x >> 6] = n2;
    __syncthreads();
    const float tot = wsum[0] + wsum[1] + wsum[2] + wsum[3];

    E[(size_t)bs * D_ + d] = sum / sqrtf(tot);

    if (threadIdx.x == 0) {
        float c = 0.f;
        for (int i = 0; i < NC1; ++i) c += Cp[(size_t)bs * NC1 + i];
        ACT[bs] = c;
        const int b = bs / S_, s = bs % S_;
        IDX[bs] = ss[b * S_ + sigmas[b * S_ + s]];
    }
}

// ---------------------------------------------------------------- kernel G
// Dense pass: dots[v][bs] = (table[v] . e[bs]) / ||table[v]||  for ALL v.
// Table streamed ONCE coalesced (no gather). 64 rows x 64 cols per block,
// d-chunk=32 LDS staging, 4x4 register tile, stride-16 row/col ownership
// (<=2-way LDS conflicts), row norms fused on col-group-0 threads.
__global__ __launch_bounds__(256) void kG_dots(
    const float* __restrict__ table, const float* __restrict__ E,
    float* __restrict__ dots)
{
    const int v0  = blockIdx.x * GR;
    const int tid = threadIdx.x;

    __shared__ float rowsL[GR][GPAD];
    __shared__ float eL[64][GPAD];
    __shared__ float n2L[GR];

    const int rg = tid & 15;     // rows rg+16*ri
    const int cg = tid >> 4;     // cols cg+16*ci
    const int sr = tid >> 3;     // staging row 0..31 (and +32)
    const int ssl = tid & 7;     // staging float4 slot

    float acc[4][4];
    float n2[4];
    #pragma unroll
    for (int i = 0; i < 4; ++i) {
        n2[i] = 0.f;
        #pragma unroll
        for (int j = 0; j < 4; ++j) acc[i][j] = 0.f;
    }

    for (int ch = 0; ch < D_ / GDCH; ++ch) {
        const int d0 = ch * GDCH;
        if (ch) __syncthreads();
        // stage 64 table rows (guarded) + 64 e rows, chunk [d0, d0+32)
        #pragma unroll
        for (int h = 0; h < 2; ++h) {
            const int r  = sr + 32 * h;
            const int gv = v0 + r;
            float4 v = make_float4(0.f, 0.f, 0.f, 0.f);
            if (gv < V_) v = *(const float4*)(table + (size_t)gv * D_ + d0 + ssl * 4);
            *(float4*)&rowsL[r][ssl * 4] = v;
            *(float4*)&eL[r][ssl * 4] =
                *(const float4*)(E + (size_t)r * D_ + d0 + ssl * 4);
        }
        __syncthreads();

        #pragma unroll
        for (int dk = 0; dk < GDCH; dk += 4) {
            float4 rv[4], cv[4];
            #pragma unroll
            for (int ri = 0; ri < 4; ++ri)
                rv[ri] = *(const float4*)&rowsL[rg + 16 * ri][dk];
            #pragma unroll
            for (int ci = 0; ci < 4; ++ci)
                cv[ci] = *(const float4*)&eL[cg + 16 * ci][dk];
            #pragma unroll
            for (int ri = 0; ri < 4; ++ri) {
                #pragma unroll
                for (int ci = 0; ci < 4; ++ci)
                    acc[ri][ci] += rv[ri].x * cv[ci].x + rv[ri].y * cv[ci].y
                                 + rv[ri].z * cv[ci].z + rv[ri].w * cv[ci].w;
                if (cg == 0)
                    n2[ri] += rv[ri].x * rv[ri].x + rv[ri].y * rv[ri].y
                            + rv[ri].z * rv[ri].z + rv[ri].w * rv[ri].w;
            }
        }
    }

    if (cg == 0) {
        #pragma unroll
        for (int ri = 0; ri < 4; ++ri) n2L[rg + 16 * ri] = n2[ri];
    }
    __syncthreads();

    #pragma unroll
    for (int ri = 0; ri < 4; ++ri) {
        const int v = v0 + rg + 16 * ri;
        if (v < V_) {
            const float rinv = 1.f / sqrtf(n2L[rg + 16 * ri]);
            #pragma unroll
            for (int ci = 0; ci < 4; ++ci)
                dots[(size_t)v * 64 + cg + 16 * ci] = acc[ri][ci] * rinv;
        }
    }
}

// ---------------------------------------------------------------- kernel 3b
// Gather float4 of precomputed cos per candidate (L2/L3-resident dots).
__global__ __launch_bounds__(256) void k3b_soft(
    const float* __restrict__ dots, const int* __restrict__ ns,
    const int* __restrict__ IDX,
    const float* __restrict__ alpha_p, const float* __restrict__ beta_p,
    float* __restrict__ DT, float* __restrict__ SE)
{
    const int b     = blockIdx.x / NCSE;
    const int chunk = blockIdx.x % NCSE;
    const int tid   = threadIdx.x;
    const int wid   = tid >> 6;
    const int lane  = tid & 63;

    const float alpha = fmaxf(alpha_p[0], 2.220446049250313e-16f);
    const float beta  = beta_p[0];

    const int n  = chunk * CPSE + tid;
    const int id = ns[b * N_ + n];
    const float4 c4 = *(const float4*)(dots + (size_t)id * 64 + b * 4);
    const float cos4[4] = {c4.x, c4.y, c4.z, c4.w};

    float se[S_];
    #pragma unroll
    for (int s2 = 0; s2 < S_; ++s2) {
        const float dist2 = fmaxf(2.f - 2.f * cos4[s2], 0.f);
        const float dd    = alpha * dist2 + beta;
        se[s2] = expf(-dd);
        if (n == IDX[b * S_ + s2]) DT[b * S_ + s2] = dd;   // unique writer
    }

    #pragma unroll
    for (int o = 1; o <= 32; o <<= 1) {
        #pragma unroll
        for (int s2 = 0; s2 < S_; ++s2) se[s2] += __shfl_xor(se[s2], o, 64);
    }
    __shared__ float sse[4][S_];
    if (lane == 0) {
        #pragma unroll
        for (int s2 = 0; s2 < S_; ++s2) sse[wid][s2] = se[s2];
    }
    __syncthreads();
    if (tid < S_)
        SE[((size_t)b * NCSE + chunk) * S_ + tid] =
            sse[0][tid] + sse[1][tid] + sse[2][tid] + sse[3][tid];
}

// ---------------------------------------------------------------- kernel 3 (fallback)
// R3-style direct gather, used only if ws is too small for dots[].
__global__ __launch_bounds__(256) void k3_gather(
    const float* __restrict__ table, const int* __restrict__ ns,
    const float* __restrict__ E, const int* __restrict__ IDX,
    const float* __restrict__ alpha_p, const float* __restrict__ beta_p,
    float* __restrict__ DT, float* __restrict__ SE)
{
    const int b     = blockIdx.x / NCSE;
    const int chunk = blockIdx.x % NCSE;
    const int wid  = threadIdx.x >> 6;
    const int lane = threadIdx.x & 63;

    __shared__ float e_s[S_ * D_];
    for (int i = threadIdx.x; i < S_ * D_; i += 256)
        e_s[i] = E[(size_t)b * S_ * D_ + i];
    __syncthreads();

    const float alpha = fmaxf(alpha_p[0], 2.220446049250313e-16f);
    const float beta  = beta_p[0];
    int tgt[S_];
    #pragma unroll
    for (int s2 = 0; s2 < S_; ++s2) tgt[s2] = IDX[b * S_ + s2];

    const int n  = chunk * CPSE + threadIdx.x;
    const int id = ns[b * N_ + n];
    const float* __restrict__ row = table + (size_t)id * D_;

    float n2 = 0.f;
    float dp[S_] = {0.f, 0.f, 0.f, 0.f};
    #pragma unroll 4
    for (int d = 0; d < D_; d += 4) {
        const float4 v = *(const float4*)(row + d);
        n2 += v.x * v.x + v.y * v.y + v.z * v.z + v.w * v.w;
        #pragma unroll
        for (int s2 = 0; s2 < S_; ++s2) {
            const float4 e4 = *(const float4*)(e_s + s2 * D_ + d);
            dp[s2] += e4.x * v.x + e4.y * v.y + e4.z * v.z + e4.w * v.w;
        }
    }

    const float invn = 1.f / sqrtf(n2);
    float se[S_];
    #pragma unroll
    for (int s2 = 0; s2 < S_; ++s2) {
        const float cosv  = dp[s2] * invn;
        const float dist2 = fmaxf(2.f - 2.f * cosv, 0.f);
        const float dd    = alpha * dist2 + beta;
        se[s2] = expf(-dd);
        if (n == tgt[s2]) DT[b * S_ + s2] = dd;
    }

    #pragma unroll
    for (int o = 1; o <= 32; o <<= 1) {
        #pragma unroll
        for (int s2 = 0; s2 < S_; ++s2) se[s2] += __shfl_xor(se[s2], o, 64);
    }
    __shared__ float sse[4][S_];
    if (lane == 0) {
        #pragma unroll
        for (int s2 = 0; s2 < S_; ++s2) sse[wid][s2] = se[s2];
    }
    __syncthreads();
    if (threadIdx.x < S_)
        SE[((size_t)b * NCSE + chunk) * S_ + threadIdx.x] =
            sse[0][threadIdx.x] + sse[1][threadIdx.x] +
            sse[2][threadIdx.x] + sse[3][threadIdx.x];
}

// ---------------------------------------------------------------- kernel 4
__global__ __launch_bounds__(64) void k4_final(
    const float* __restrict__ SE, const float* __restrict__ DT,
    const float* __restrict__ ACT, float* __restrict__ out)
{
    const int bs = threadIdx.x;           // 0..63
    const int b = bs / S_, s = bs % S_;
    double sum = 0.0;
    for (int c = 0; c < NCSE; ++c) sum += (double)SE[((size_t)b * NCSE + c) * S_ + s];
    float loss = DT[bs] + (float)log(sum);
    if (!(ACT[bs] > 0.f)) loss = 0.f;
    float v = loss;
    #pragma unroll
    for (int o = 32; o >= 1; o >>= 1) v += __shfl_xor(v, o, 64);
    if (bs == 0) out[0] = v / 64.f;
}

// ---------------------------------------------------------------- launch
extern "C" void kernel_launch(void* const* d_in, const int* in_sizes, int n_in,
                              void* d_out, int out_size, void* d_ws, size_t ws_size,
                              hipStream_t stream)
{
    const float* spks   = (const float*)d_in[0];
    // d_in[1] = ys (unused)
    const float* ts     = (const float*)d_in[2];
    const int*   ss     = (const int*)  d_in[3];
    const int*   sigmas = (const int*)  d_in[4];
    const int*   ns     = (const int*)  d_in[5];
    const int*   ilens  = (const int*)  d_in[6];
    const float* table  = (const float*)d_in[7];
    const float* alpha  = (const float*)d_in[8];
    const float* beta   = (const float*)d_in[9];
    float* out = (float*)d_out;

    float* ws = (float*)d_ws;
    float* Wp  = ws + OFF_W;
    float* Cp  = ws + OFF_CNT;
    float* E   = ws + OFF_E;
    int*   IDX = (int*)(ws + OFF_IDX);
    float* ACT = ws + OFF_ACT;
    float* DT  = ws + OFF_DT;
    float* SE  = ws + OFF_SE;
    float* DOT = ws + OFF_DOT;

    k1_frames<<<64 * NC1, 256, 0, stream>>>(spks, ts, sigmas, ilens, Wp, Cp);
    k2_evec  <<<64,       256, 0, stream>>>(Wp, Cp, ss, sigmas, E, IDX, ACT);

    if (ws_size >= WS_FULL_FLOATS * sizeof(float)) {
        kG_dots <<<GNB,        256, 0, stream>>>(table, E, DOT);
        k3b_soft<<<B_ * NCSE,  256, 0, stream>>>(DOT, ns, IDX, alpha, beta, DT, SE);
    } else {
        k3_gather<<<B_ * NCSE, 256, 0, stream>>>(table, ns, E, IDX, alpha, beta, DT, SE);
    }
    k4_final <<<1, 64, 0, stream>>>(SE, DT, ACT, out);
}

// Round 8
// 45.698 us; speedup vs baseline: 2.7314x; 2.7314x over previous
//
#include <hip/hip_runtime.h>
#include <math.h>

#define B_ 16
#define S_ 4
#define T_ 1000
#define D_ 256
#define N_ 8192
#define V_ 50000

constexpr int NC1 = 20;              // chunks over T for k1
constexpr int TC1 = (T_ + NC1 - 1) / NC1;  // 50 frames per chunk
constexpr int K3B = 128;             // blocks per batch item in k3
constexpr int K3C = N_ / K3B;        // 64 candidates per block
constexpr int K3P = K3C / 16;        // 4 passes (16 candidates per pass)

// ws layout (float units)
constexpr size_t OFF_W   = 0;                                // [64][NC1][D]
constexpr size_t OFF_CNT = OFF_W   + (size_t)64*NC1*D_;      // [64][NC1]
constexpr size_t OFF_E   = OFF_CNT + (size_t)64*NC1;         // [64][D]
constexpr size_t OFF_IDX = OFF_E   + (size_t)64*D_;          // [64] int
constexpr size_t OFF_ACT = OFF_IDX + 64;                     // [64]
constexpr size_t OFF_DT  = OFF_ACT + 64;                     // [64]
constexpr size_t OFF_SE  = OFF_DT  + 64;                     // [B][K3B][S]

// ---------------------------------------------------------------- kernel 1
__global__ __launch_bounds__(256) void k1_frames(
    const float* __restrict__ spks, const float* __restrict__ ts,
    const int* __restrict__ sigmas, const int* __restrict__ ilens,
    float* __restrict__ Wp, float* __restrict__ Cp)
{
    const int blk   = blockIdx.x;
    const int bs    = blk / NC1;
    const int chunk = blk % NC1;
    const int b = bs / S_, s = bs % S_;
    const int sig  = sigmas[b * S_ + s];
    const int ilen = ilens[b];
    const int t0 = chunk * TC1;
    int t1 = t0 + TC1; if (t1 > T_) t1 = T_; if (t1 > ilen) t1 = ilen;

    const int wid  = threadIdx.x >> 6;
    const int lane = threadIdx.x & 63;

    float4 acc = make_float4(0.f, 0.f, 0.f, 0.f);
    float  cnt = 0.f;
    const float* base = spks + (size_t)bs * T_ * D_;

    for (int t = t0 + wid; t < t1; t += 4) {
        float4 v = *(const float4*)(base + (size_t)t * D_ + lane * 4);
        float n2 = v.x * v.x + v.y * v.y + v.z * v.z + v.w * v.w;
        #pragma unroll
        for (int o = 32; o >= 1; o >>= 1) n2 += __shfl_xor(n2, o, 64);
        const float w = ts[(b * T_ + t) * S_ + sig];
        const float scale = w / sqrtf(n2);
        acc.x += v.x * scale; acc.y += v.y * scale;
        acc.z += v.z * scale; acc.w += v.w * scale;
        if (lane == 0) cnt += rintf(w);
    }

    __shared__ float sacc[4][D_];
    __shared__ float scnt[4];
    sacc[wid][lane * 4 + 0] = acc.x;
    sacc[wid][lane * 4 + 1] = acc.y;
    sacc[wid][lane * 4 + 2] = acc.z;
    sacc[wid][lane * 4 + 3] = acc.w;
    if (lane == 0) scnt[wid] = cnt;
    __syncthreads();

    const int d = threadIdx.x;
    const float sum = sacc[0][d] + sacc[1][d] + sacc[2][d] + sacc[3][d];
    Wp[((size_t)bs * NC1 + chunk) * D_ + d] = sum;
    if (threadIdx.x == 0)
        Cp[(size_t)bs * NC1 + chunk] = scnt[0] + scnt[1] + scnt[2] + scnt[3];
}

// ---------------------------------------------------------------- kernel 2
__global__ __launch_bounds__(256) void k2_evec(
    const float* __restrict__ Wp, const float* __restrict__ Cp,
    const int* __restrict__ ss, const int* __restrict__ sigmas,
    float* __restrict__ E, int* __restrict__ IDX, float* __restrict__ ACT)
{
    const int bs = blockIdx.x;
    const int d  = threadIdx.x;
    float sum = 0.f;
    for (int c = 0; c < NC1; ++c) sum += Wp[((size_t)bs * NC1 + c) * D_ + d];

    float n2 = sum * sum;
    #pragma unroll
    for (int o = 32; o >= 1; o >>= 1) n2 += __shfl_xor(n2, o, 64);
    __shared__ float wsum[4];
    if ((threadIdx.x & 63) == 0) wsum[threadIdx.x >> 6] = n2;
    __syncthreads();
    const float tot = wsum[0] + wsum[1] + wsum[2] + wsum[3];

    E[(size_t)bs * D_ + d] = sum / sqrtf(tot);

    if (threadIdx.x == 0) {
        float c = 0.f;
        for (int i = 0; i < NC1; ++i) c += Cp[(size_t)bs * NC1 + i];
        ACT[bs] = c;
        const int b = bs / S_, s = bs % S_;
        IDX[bs] = ss[b * S_ + sigmas[b * S_ + s]];
    }
}

// ---------------------------------------------------------------- kernel 3
// grid: (B*K3B)=2048 blocks x 256 threads. 16 lanes per candidate; lane q
// owns d-slice {i*64 + q*4 .. +3}. e-fragments live in REGISTERS (64 VGPR,
// loaded once per thread) -> NO LDS, NO barriers in the loop. Global loads
// are 256B-contiguous per 16-lane group (coalesced, full line consumption).
// Per-candidate reduction: 4-stage butterfly (masks 1,2,4,8), amortized
// over 4 simultaneous candidates per wave.
__global__ __launch_bounds__(256) void k3_dist(
    const float* __restrict__ table, const int* __restrict__ ns,
    const float* __restrict__ E, const int* __restrict__ IDX,
    const float* __restrict__ alpha_p, const float* __restrict__ beta_p,
    float* __restrict__ DT, float* __restrict__ SE)
{
    const int b     = blockIdx.x / K3B;
    const int chunk = blockIdx.x % K3B;
    const int tid   = threadIdx.x;
    const int wid   = tid >> 6;
    const int lane  = tid & 63;
    const int q     = lane & 15;         // slice owner within candidate
    const int g     = lane >> 4;         // candidate group within wave

    // e-fragment: ef[s][i] = E[(b*S+s)*D + i*64 + q*4 ..+3]
    float4 ef[S_][4];
    #pragma unroll
    for (int s2 = 0; s2 < S_; ++s2)
        #pragma unroll
        for (int i = 0; i < 4; ++i)
            ef[s2][i] = *(const float4*)(E + (size_t)(b * S_ + s2) * D_ + i * 64 + q * 4);

    const float alpha = fmaxf(alpha_p[0], 2.220446049250313e-16f);
    const float beta  = beta_p[0];
    int tgt[S_];
    #pragma unroll
    for (int s2 = 0; s2 < S_; ++s2) tgt[s2] = IDX[b * S_ + s2];

    float se[S_] = {0.f, 0.f, 0.f, 0.f};
    const int n0 = chunk * K3C;
    const int* __restrict__ nsb = ns + b * N_;

    for (int p = 0; p < K3P; ++p) {
        const int n  = n0 + p * 16 + wid * 4 + g;
        const int id = nsb[n];                        // broadcast within group
        const float* __restrict__ row = table + (size_t)id * D_;

        float n2 = 0.f;
        float dp[S_] = {0.f, 0.f, 0.f, 0.f};
        #pragma unroll
        for (int i = 0; i < 4; ++i) {
            const float4 v = *(const float4*)(row + i * 64 + q * 4);
            n2 += v.x * v.x + v.y * v.y + v.z * v.z + v.w * v.w;
            #pragma unroll
            for (int s2 = 0; s2 < S_; ++s2) {
                const float4 e4 = ef[s2][i];
                dp[s2] += e4.x * v.x + e4.y * v.y + e4.z * v.z + e4.w * v.w;
            }
        }

        // 16-lane butterfly: all lanes of the group get candidate totals
        #pragma unroll
        for (int o = 1; o <= 8; o <<= 1) {
            n2 += __shfl_xor(n2, o, 64);
            #pragma unroll
            for (int s2 = 0; s2 < S_; ++s2) dp[s2] += __shfl_xor(dp[s2], o, 64);
        }

        const float invn = 1.f / sqrtf(n2);
        #pragma unroll
        for (int s2 = 0; s2 < S_; ++s2) {
            const float cosv  = dp[s2] * invn;
            const float dist2 = fmaxf(2.f - 2.f * cosv, 0.f);
            const float dd    = alpha * dist2 + beta;
            se[s2] += expf(-dd);              // identical within group
            if (q == 0 && n == tgt[s2]) DT[b * S_ + s2] = dd;  // unique writer
        }
    }

    // masks 16,32 sum the 4 groups (within-group copies identical)
    #pragma unroll
    for (int o = 16; o <= 32; o <<= 1) {
        #pragma unroll
        for (int s2 = 0; s2 < S_; ++s2) se[s2] += __shfl_xor(se[s2], o, 64);
    }
    __shared__ float sse[4][S_];
    if (lane == 0) {
        #pragma unroll
        for (int s2 = 0; s2 < S_; ++s2) sse[wid][s2] = se[s2];
    }
    __syncthreads();
    if (tid < S_)
        SE[((size_t)(b * K3B + chunk)) * S_ + tid] =
            sse[0][tid] + sse[1][tid] + sse[2][tid] + sse[3][tid];
}

// ---------------------------------------------------------------- kernel 4
__global__ __launch_bounds__(64) void k4_final(
    const float* __restrict__ SE, const float* __restrict__ DT,
    const float* __restrict__ ACT, float* __restrict__ out)
{
    const int bs = threadIdx.x;           // 0..63
    const int b = bs / S_, s = bs % S_;
    double sum = 0.0;
    for (int c = 0; c < K3B; ++c) sum += (double)SE[((size_t)(b * K3B + c)) * S_ + s];
    float loss = DT[bs] + (float)log(sum);
    if (!(ACT[bs] > 0.f)) loss = 0.f;
    float v = loss;
    #pragma unroll
    for (int o = 32; o >= 1; o >>= 1) v += __shfl_xor(v, o, 64);
    if (bs == 0) out[0] = v / 64.f;
}

// ---------------------------------------------------------------- launch
extern "C" void kernel_launch(void* const* d_in, const int* in_sizes, int n_in,
                              void* d_out, int out_size, void* d_ws, size_t ws_size,
                              hipStream_t stream)
{
    const float* spks   = (const float*)d_in[0];
    // d_in[1] = ys (unused)
    const float* ts     = (const float*)d_in[2];
    const int*   ss     = (const int*)  d_in[3];
    const int*   sigmas = (const int*)  d_in[4];
    const int*   ns     = (const int*)  d_in[5];
    const int*   ilens  = (const int*)  d_in[6];
    const float* table  = (const float*)d_in[7];
    const float* alpha  = (const float*)d_in[8];
    const float* beta   = (const float*)d_in[9];
    float* out = (float*)d_out;

    float* ws = (float*)d_ws;
    float* Wp  = ws + OFF_W;
    float* Cp  = ws + OFF_CNT;
    float* E   = ws + OFF_E;
    int*   IDX = (int*)(ws + OFF_IDX);
    float* ACT = ws + OFF_ACT;
    float* DT  = ws + OFF_DT;
    float* SE  = ws + OFF_SE;

    k1_frames<<<64 * NC1, 256, 0, stream>>>(spks, ts, sigmas, ilens, Wp, Cp);
    k2_evec  <<<64,       256, 0, stream>>>(Wp, Cp, ss, sigmas, E, IDX, ACT);
    k3_dist  <<<B_ * K3B, 256, 0, stream>>>(table, ns, E, IDX, alpha, beta, DT, SE);
    k4_final <<<1,         64, 0, stream>>>(SE, DT, ACT, out);
}

// Round 9
// 41.555 us; speedup vs baseline: 3.0036x; 1.0997x over previous
//
#include <hip/hip_runtime.h>
#include <math.h>

#define B_ 16
#define S_ 4
#define T_ 1000
#define D_ 256
#define N_ 8192
#define V_ 50000

constexpr int NC1 = 20;              // chunks over T for k1
constexpr int TC1 = (T_ + NC1 - 1) / NC1;  // 50 frames per chunk
constexpr int NCSE = 32;             // SE chunks over N
constexpr int CPSE = N_ / NCSE;      // 256 candidates per chunk
constexpr int GNB  = (V_ + 63) / 64; // 782 blocks for kG (64 rows each)

// ws layout (float units) — small arrays FIRST so fallback fits
constexpr size_t OFF_W   = 0;                                // [64][NC1][D]
constexpr size_t OFF_CNT = OFF_W   + (size_t)64*NC1*D_;      // [64][NC1]
constexpr size_t OFF_E   = OFF_CNT + (size_t)64*NC1;         // [64][D]
constexpr size_t OFF_IDX = OFF_E   + (size_t)64*D_;          // [64] int
constexpr size_t OFF_ACT = OFF_IDX + 64;                     // [64]
constexpr size_t OFF_DT  = OFF_ACT + 64;                     // [64]
constexpr size_t OFF_SE  = OFF_DT  + 64;                     // [B][NCSE][S]
constexpr size_t OFF_DOT = OFF_SE  + (size_t)B_*NCSE*S_;     // [V][64]
constexpr size_t OFF_N2  = OFF_DOT + (size_t)V_*64;          // [V]
constexpr size_t WS_FULL_FLOATS = OFF_N2 + V_;

typedef __attribute__((ext_vector_type(8))) short bf16x8;
typedef __attribute__((ext_vector_type(4))) float f32x4;

__device__ inline unsigned short f2bf(float x) {   // RNE f32->bf16
    unsigned int u = __float_as_uint(x);
    return (unsigned short)((u + 0x7FFFu + ((u >> 16) & 1u)) >> 16);
}

// ---------------------------------------------------------------- kernel 1
__global__ __launch_bounds__(256) void k1_frames(
    const float* __restrict__ spks, const float* __restrict__ ts,
    const int* __restrict__ sigmas, const int* __restrict__ ilens,
    float* __restrict__ Wp, float* __restrict__ Cp)
{
    const int blk   = blockIdx.x;
    const int bs    = blk / NC1;
    const int chunk = blk % NC1;
    const int b = bs / S_, s = bs % S_;
    const int sig  = sigmas[b * S_ + s];
    const int ilen = ilens[b];
    const int t0 = chunk * TC1;
    int t1 = t0 + TC1; if (t1 > T_) t1 = T_; if (t1 > ilen) t1 = ilen;

    const int wid  = threadIdx.x >> 6;
    const int lane = threadIdx.x & 63;

    float4 acc = make_float4(0.f, 0.f, 0.f, 0.f);
    float  cnt = 0.f;
    const float* base = spks + (size_t)bs * T_ * D_;

    for (int t = t0 + wid; t < t1; t += 4) {
        float4 v = *(const float4*)(base + (size_t)t * D_ + lane * 4);
        float n2 = v.x * v.x + v.y * v.y + v.z * v.z + v.w * v.w;
        #pragma unroll
        for (int o = 32; o >= 1; o >>= 1) n2 += __shfl_xor(n2, o, 64);
        const float w = ts[(b * T_ + t) * S_ + sig];
        const float scale = w / sqrtf(n2);
        acc.x += v.x * scale; acc.y += v.y * scale;
        acc.z += v.z * scale; acc.w += v.w * scale;
        if (lane == 0) cnt += rintf(w);
    }

    __shared__ float sacc[4][D_];
    __shared__ float scnt[4];
    sacc[wid][lane * 4 + 0] = acc.x;
    sacc[wid][lane * 4 + 1] = acc.y;
    sacc[wid][lane * 4 + 2] = acc.z;
    sacc[wid][lane * 4 + 3] = acc.w;
    if (lane == 0) scnt[wid] = cnt;
    __syncthreads();

    const int d = threadIdx.x;
    const float sum = sacc[0][d] + sacc[1][d] + sacc[2][d] + sacc[3][d];
    Wp[((size_t)bs * NC1 + chunk) * D_ + d] = sum;
    if (threadIdx.x == 0)
        Cp[(size_t)bs * NC1 + chunk] = scnt[0] + scnt[1] + scnt[2] + scnt[3];
}

// ---------------------------------------------------------------- kernel 2
__global__ __launch_bounds__(256) void k2_evec(
    const float* __restrict__ Wp, const float* __restrict__ Cp,
    const int* __restrict__ ss, const int* __restrict__ sigmas,
    float* __restrict__ E, int* __restrict__ IDX, float* __restrict__ ACT)
{
    const int bs = blockIdx.x;
    const int d  = threadIdx.x;
    float sum = 0.f;
    for (int c = 0; c < NC1; ++c) sum += Wp[((size_t)bs * NC1 + c) * D_ + d];

    float n2 = sum * sum;
    #pragma unroll
    for (int o = 32; o >= 1; o >>= 1) n2 += __shfl_xor(n2, o, 64);
    __shared__ float wsum[4];
    if ((threadIdx.x & 63) == 0) wsum[threadIdx.x >> 6] = n2;
    __syncthreads();
    const float tot = wsum[0] + wsum[1] + wsum[2] + wsum[3];

    E[(size_t)bs * D_ + d] = sum / sqrtf(tot);

    if (threadIdx.x == 0) {
        float c = 0.f;
        for (int i = 0; i < NC1; ++i) c += Cp[(size_t)bs * NC1 + i];
        ACT[bs] = c;
        const int b = bs / S_, s = bs % S_;
        IDX[bs] = ss[b * S_ + sigmas[b * S_ + s]];
    }
}

// ---------------------------------------------------------------- kernel G
// Dense bf16-MFMA: dots[v][bs] = table[v].e[bs] (raw), N2[v] = ||table[v]||^2.
// Per wave: 16 table rows, K=256. A-frag straight from global f32 (lane l:
// row v0+(l&15), k = 8*(l>>4)+j -> 16 full 128B lines per load pair), RNE
// cvt to bf16 in-register. e staged once to bf16 LDS [64][264] (pad -> 2-way
// max). 4 col-group MFMAs per K-step. Table read ONCE, coalesced: HBM-bound.
__global__ __launch_bounds__(256) void kG_mfma(
    const float* __restrict__ table, const float* __restrict__ E,
    float* __restrict__ dots, float* __restrict__ N2v)
{
    __shared__ unsigned short e_lds[64][264];
    const int tid = threadIdx.x;

    // stage E (f32 [64][256]) -> bf16 LDS
    {
        const float4* Ef4 = (const float4*)E;
        for (int idx = tid; idx < 64 * 64; idx += 256) {
            const int bs = idx >> 6, p = idx & 63;
            const float4 v = Ef4[idx];
            unsigned short* dst = &e_lds[bs][p * 4];
            dst[0] = f2bf(v.x); dst[1] = f2bf(v.y);
            dst[2] = f2bf(v.z); dst[3] = f2bf(v.w);
        }
    }
    __syncthreads();

    const int wv = tid >> 6, l = tid & 63;
    const int lr = l & 15;               // row within 16 / col within 16
    const int lk = l >> 4;               // k-block
    const int v0 = blockIdx.x * 64 + wv * 16;
    const int vr = v0 + lr;
    const int vload = (vr < V_) ? vr : 0;
    const float* __restrict__ rowp = table + (size_t)vload * D_ + 8 * lk;

    f32x4 acc[4] = {{0.f,0.f,0.f,0.f},{0.f,0.f,0.f,0.f},
                    {0.f,0.f,0.f,0.f},{0.f,0.f,0.f,0.f}};
    float n2 = 0.f;

    #pragma unroll
    for (int ks = 0; ks < 8; ++ks) {
        const float4 lo = *(const float4*)(rowp + ks * 32);
        const float4 hi = *(const float4*)(rowp + ks * 32 + 4);
        n2 += lo.x*lo.x + lo.y*lo.y + lo.z*lo.z + lo.w*lo.w
            + hi.x*hi.x + hi.y*hi.y + hi.z*hi.z + hi.w*hi.w;
        bf16x8 a;
        a[0] = (short)f2bf(lo.x); a[1] = (short)f2bf(lo.y);
        a[2] = (short)f2bf(lo.z); a[3] = (short)f2bf(lo.w);
        a[4] = (short)f2bf(hi.x); a[5] = (short)f2bf(hi.y);
        a[6] = (short)f2bf(hi.z); a[7] = (short)f2bf(hi.w);
        #pragma unroll
        for (int cg = 0; cg < 4; ++cg) {
            const bf16x8 bf = *(const bf16x8*)&e_lds[cg * 16 + lr][ks * 32 + 8 * lk];
            acc[cg] = __builtin_amdgcn_mfma_f32_16x16x32_bf16(a, bf, acc[cg], 0, 0, 0);
        }
    }

    // combine the 4 k-block partials of n2 (lanes l, l^16, l^32, l^48)
    n2 += __shfl_xor(n2, 16, 64);
    n2 += __shfl_xor(n2, 32, 64);
    if (l < 16 && vr < V_) N2v[vr] = n2;

    // D: col = lane&15, row = (lane>>4)*4 + r  [m89-verified]
    #pragma unroll
    for (int cg = 0; cg < 4; ++cg) {
        #pragma unroll
        for (int r = 0; r < 4; ++r) {
            const int v = v0 + 4 * lk + r;
            if (v < V_) dots[(size_t)v * 64 + cg * 16 + lr] = acc[cg][r];
        }
    }
}

// ---------------------------------------------------------------- kernel 3b
// Gather float4 of raw dots + n2 scalar; cos = dot * rsqrt(n2).
__global__ __launch_bounds__(256) void k3b_soft(
    const float* __restrict__ dots, const float* __restrict__ N2v,
    const int* __restrict__ ns, const int* __restrict__ IDX,
    const float* __restrict__ alpha_p, const float* __restrict__ beta_p,
    float* __restrict__ DT, float* __restrict__ SE)
{
    const int b     = blockIdx.x / NCSE;
    const int chunk = blockIdx.x % NCSE;
    const int tid   = threadIdx.x;
    const int wid   = tid >> 6;
    const int lane  = tid & 63;

    const float alpha = fmaxf(alpha_p[0], 2.220446049250313e-16f);
    const float beta  = beta_p[0];

    const int n  = chunk * CPSE + tid;
    const int id = ns[b * N_ + n];
    const float4 c4 = *(const float4*)(dots + (size_t)id * 64 + b * 4);
    const float invn = rsqrtf(N2v[id]);
    const float cos4[4] = {c4.x * invn, c4.y * invn, c4.z * invn, c4.w * invn};

    float se[S_];
    #pragma unroll
    for (int s2 = 0; s2 < S_; ++s2) {
        const float dist2 = fmaxf(2.f - 2.f * cos4[s2], 0.f);
        const float dd    = alpha * dist2 + beta;
        se[s2] = expf(-dd);
        if (n == IDX[b * S_ + s2]) DT[b * S_ + s2] = dd;   // unique writer
    }

    #pragma unroll
    for (int o = 1; o <= 32; o <<= 1) {
        #pragma unroll
        for (int s2 = 0; s2 < S_; ++s2) se[s2] += __shfl_xor(se[s2], o, 64);
    }
    __shared__ float sse[4][S_];
    if (lane == 0) {
        #pragma unroll
        for (int s2 = 0; s2 < S_; ++s2) sse[wid][s2] = se[s2];
    }
    __syncthreads();
    if (tid < S_)
        SE[((size_t)b * NCSE + chunk) * S_ + tid] =
            sse[0][tid] + sse[1][tid] + sse[2][tid] + sse[3][tid];
}

// ---------------------------------------------------------------- kernel 3 (fallback)
__global__ __launch_bounds__(256) void k3_gather(
    const float* __restrict__ table, const int* __restrict__ ns,
    const float* __restrict__ E, const int* __restrict__ IDX,
    const float* __restrict__ alpha_p, const float* __restrict__ beta_p,
    float* __restrict__ DT, float* __restrict__ SE)
{
    const int b     = blockIdx.x / NCSE;
    const int chunk = blockIdx.x % NCSE;
    const int wid  = threadIdx.x >> 6;
    const int lane = threadIdx.x & 63;

    __shared__ float e_s[S_ * D_];
    for (int i = threadIdx.x; i < S_ * D_; i += 256)
        e_s[i] = E[(size_t)b * S_ * D_ + i];
    __syncthreads();

    const float alpha = fmaxf(alpha_p[0], 2.220446049250313e-16f);
    const float beta  = beta_p[0];
    int tgt[S_];
    #pragma unroll
    for (int s2 = 0; s2 < S_; ++s2) tgt[s2] = IDX[b * S_ + s2];

    const int n  = chunk * CPSE + threadIdx.x;
    const int id = ns[b * N_ + n];
    const float* __restrict__ row = table + (size_t)id * D_;

    float n2 = 0.f;
    float dp[S_] = {0.f, 0.f, 0.f, 0.f};
    #pragma unroll 4
    for (int d = 0; d < D_; d += 4) {
        const float4 v = *(const float4*)(row + d);
        n2 += v.x * v.x + v.y * v.y + v.z * v.z + v.w * v.w;
        #pragma unroll
        for (int s2 = 0; s2 < S_; ++s2) {
            const float4 e4 = *(const float4*)(e_s + s2 * D_ + d);
            dp[s2] += e4.x * v.x + e4.y * v.y + e4.z * v.z + e4.w * v.w;
        }
    }

    const float invn = 1.f / sqrtf(n2);
    float se[S_];
    #pragma unroll
    for (int s2 = 0; s2 < S_; ++s2) {
        const float cosv  = dp[s2] * invn;
        const float dist2 = fmaxf(2.f - 2.f * cosv, 0.f);
        const float dd    = alpha * dist2 + beta;
        se[s2] = expf(-dd);
        if (n == tgt[s2]) DT[b * S_ + s2] = dd;
    }

    #pragma unroll
    for (int o = 1; o <= 32; o <<= 1) {
        #pragma unroll
        for (int s2 = 0; s2 < S_; ++s2) se[s2] += __shfl_xor(se[s2], o, 64);
    }
    __shared__ float sse[4][S_];
    if (lane == 0) {
        #pragma unroll
        for (int s2 = 0; s2 < S_; ++s2) sse[wid][s2] = se[s2];
    }
    __syncthreads();
    if (threadIdx.x < S_)
        SE[((size_t)b * NCSE + chunk) * S_ + threadIdx.x] =
            sse[0][threadIdx.x] + sse[1][threadIdx.x] +
            sse[2][threadIdx.x] + sse[3][threadIdx.x];
}

// ---------------------------------------------------------------- kernel 4
__global__ __launch_bounds__(64) void k4_final(
    const float* __restrict__ SE, const float* __restrict__ DT,
    const float* __restrict__ ACT, float* __restrict__ out)
{
    const int bs = threadIdx.x;           // 0..63
    const int b = bs / S_, s = bs % S_;
    double sum = 0.0;
    for (int c = 0; c < NCSE; ++c) sum += (double)SE[((size_t)b * NCSE + c) * S_ + s];
    float loss = DT[bs] + (float)log(sum);
    if (!(ACT[bs] > 0.f)) loss = 0.f;
    float v = loss;
    #pragma unroll
    for (int o = 32; o >= 1; o >>= 1) v += __shfl_xor(v, o, 64);
    if (bs == 0) out[0] = v / 64.f;
}

// ---------------------------------------------------------------- launch
extern "C" void kernel_launch(void* const* d_in, const int* in_sizes, int n_in,
                              void* d_out, int out_size, void* d_ws, size_t ws_size,
                              hipStream_t stream)
{
    const float* spks   = (const float*)d_in[0];
    // d_in[1] = ys (unused)
    const float* ts     = (const float*)d_in[2];
    const int*   ss     = (const int*)  d_in[3];
    const int*   sigmas = (const int*)  d_in[4];
    const int*   ns     = (const int*)  d_in[5];
    const int*   ilens  = (const int*)  d_in[6];
    const float* table  = (const float*)d_in[7];
    const float* alpha  = (const float*)d_in[8];
    const float* beta   = (const float*)d_in[9];
    float* out = (float*)d_out;

    float* ws = (float*)d_ws;
    float* Wp  = ws + OFF_W;
    float* Cp  = ws + OFF_CNT;
    float* E   = ws + OFF_E;
    int*   IDX = (int*)(ws + OFF_IDX);
    float* ACT = ws + OFF_ACT;
    float* DT  = ws + OFF_DT;
    float* SE  = ws + OFF_SE;
    float* DOT = ws + OFF_DOT;
    float* N2v = ws + OFF_N2;

    k1_frames<<<64 * NC1, 256, 0, stream>>>(spks, ts, sigmas, ilens, Wp, Cp);
    k2_evec  <<<64,       256, 0, stream>>>(Wp, Cp, ss, sigmas, E, IDX, ACT);

    if (ws_size >= WS_FULL_FLOATS * sizeof(float)) {
        kG_mfma <<<GNB,       256, 0, stream>>>(table, E, DOT, N2v);
        k3b_soft<<<B_ * NCSE, 256, 0, stream>>>(DOT, N2v, ns, IDX, alpha, beta, DT, SE);
    } else {
        k3_gather<<<B_ * NCSE, 256, 0, stream>>>(table, ns, E, IDX, alpha, beta, DT, SE);
    }
    k4_final <<<1, 64, 0, stream>>>(SE, DT, ACT, out);
}